// Round 3
// baseline (1354.361 us; speedup 1.0000x reference)
//
#include <hip/hip_runtime.h>

typedef float v2f __attribute__((ext_vector_type(2)));
typedef float v4f __attribute__((ext_vector_type(4)));

#define LOG2E 1.4426950408889634f
#define LN2   0.6931471805599453f

__device__ __forceinline__ float fexp2(float x) {
  float r; asm("v_exp_f32 %0, %1" : "=v"(r) : "v"(x)); return r;
}
__device__ __forceinline__ float frcp(float x) {
  float r; asm("v_rcp_f32 %0, %1" : "=v"(r) : "v"(x)); return r;
}
__device__ __forceinline__ float flog2(float x) {
  float r; asm("v_log_f32 %0, %1" : "=v"(r) : "v"(x)); return r;
}
// packed fp32 FMA (2 MACs/instr) — do not trust the compiler to emit it
__device__ __forceinline__ v2f pkfma(v2f a, v2f b, v2f c) {
  v2f d; asm("v_pk_fma_f32 %0, %1, %2, %3" : "=v"(d) : "v"(a), "v"(b), "v"(c));
  return d;
}
// quad_perm lane swaps on the VALU pipe (no LDS traffic)
__device__ __forceinline__ float dpp_xor1(float v) {
  return __builtin_bit_cast(float,
      __builtin_amdgcn_update_dpp(0, __builtin_bit_cast(int, v), 0xB1, 0xF, 0xF, true));
}
__device__ __forceinline__ float dpp_xor2(float v) {
  return __builtin_bit_cast(float,
      __builtin_amdgcn_update_dpp(0, __builtin_bit_cast(int, v), 0x4E, 0xF, 0xF, true));
}
// workgroup barrier WITHOUT the compiler's vmcnt(0) drain: LDS ordering only.
// Global prefetch/stores stay in flight across step barriers.
__device__ __forceinline__ void barrier_lgkm() {
  asm volatile("s_waitcnt lgkmcnt(0)\n\ts_barrier" ::: "memory");
}

// ---------------- embedding concat:  X[t][0..336) = [word(300) | pos(25) | 0pad] ----
__global__ void k_embed(const float* __restrict__ wv, const int* __restrict__ pidx,
                        const float* __restrict__ pemb, float* __restrict__ X) {
  int t = blockIdx.x;
  int pi = pidx[t];
  for (int c = threadIdx.x; c < 336; c += 128) {
    float v;
    if (c < 300)      v = wv[t * 300 + c];
    else if (c < 325) v = pemb[pi * 25 + (c - 300)];
    else              v = 0.f;
    X[t * 336 + c] = v;
  }
}

// ---------------- row repack with zero K-pad; optional per-gate exp2 pre-scale -----
__global__ void k_repack(const float* __restrict__ src, float* __restrict__ dst,
                         int sK, int dK, int doScale) {
  int r = blockIdx.x;
  float sc = 1.f;
  if (doScale) { int gate = (r % 500) / 125; sc = (gate == 2) ? 2.f * LOG2E : LOG2E; }
  for (int c = threadIdx.x; c < dK; c += 128)
    dst[r * dK + c] = (c < sK) ? src[r * sK + c] * sc : 0.f;
}

// ---------------- bias pre-scale (exp2 domain, per gate) ---------------------------
__global__ void k_bscale(const float* __restrict__ b, float* __restrict__ bs) {
  int i = blockIdx.x * 256 + threadIdx.x;
  if (i < 1000) {
    int gate = (i % 500) / 125;
    bs[i] = b[i] * ((gate == 2) ? 2.f * LOG2E : LOG2E);
  }
}

// ---------------- split fc1_W [100][500] -> Wab [200][256] ------------------------
__global__ void k_wab(const float* __restrict__ fc1W, float* __restrict__ Wab) {
  int r = blockIdx.x;                       // 0..199
  int sr = (r < 100) ? r : r - 100;
  int so = (r < 100) ? 0 : 250;
  for (int c = threadIdx.x; c < 256; c += 128)
    Wab[r * 256 + c] = (c < 250) ? fc1W[sr * 500 + so + c] : 0.f;
}

// ---------------- biasAB + sum(fc2_W) ----------------------------------------------
__global__ void k_misc(const float* __restrict__ fc1b, const float* __restrict__ fc2W,
                       float* __restrict__ biasAB, float* __restrict__ sumw) {
  __shared__ float red[128];
  int t = threadIdx.x;   // 128 threads
  for (int c = t; c < 256; c += 128)
    biasAB[c] = (c < 100) ? fc1b[c] : 0.f;
  float s = (t < 100) ? fc2W[t] : 0.f;
  red[t] = s; __syncthreads();
  for (int off = 64; off; off >>= 1) {
    if (t < off) red[t] += red[t + off];
    __syncthreads();
  }
  if (t == 0) sumw[0] = red[0];
}

// ---------------- tiled fp32 GEMM:  C = A @ B^T + bias -----------------------------
#define BM 64
#define BN 64
#define BKK 16
__global__ __launch_bounds__(256) void k_gemm(
    const float* __restrict__ A, const float* __restrict__ Bw,
    const float* __restrict__ bias, float* __restrict__ C,
    int M, int N, int K, int ldC, long sBz, long sCz, long sbz, int transOut) {
  const int z = blockIdx.z;
  const float* Bp = Bw + (size_t)z * sBz;
  const float* bp = bias + (size_t)z * sbz;
  float* Cp = C + (size_t)z * sCz;
  const int bm = blockIdx.y * BM, bn = blockIdx.x * BN;
  __shared__ __align__(16) float As[BKK][BM + 4];
  __shared__ __align__(16) float Bs[BKK][BN + 4];
  __shared__ float Ts[BN][BM + 1];
  const int tid = threadIdx.x;
  const int tx = tid & 15, ty = tid >> 4;
  const int lr = tid >> 2;            // 0..63
  const int lk = (tid & 3) * 4;       // 0,4,8,12
  float acc[4][4];
#pragma unroll
  for (int a = 0; a < 4; ++a)
#pragma unroll
    for (int b = 0; b < 4; ++b) acc[a][b] = 0.f;

  int brow = bn + lr; if (brow >= N) brow = N - 1;
  for (int k0 = 0; k0 < K; k0 += BKK) {
    float4 a4 = *(const float4*)(A + (size_t)(bm + lr) * K + k0 + lk);
    float4 b4 = *(const float4*)(Bp + (size_t)brow * K + k0 + lk);
    __syncthreads();
    As[lk + 0][lr] = a4.x; As[lk + 1][lr] = a4.y; As[lk + 2][lr] = a4.z; As[lk + 3][lr] = a4.w;
    Bs[lk + 0][lr] = b4.x; Bs[lk + 1][lr] = b4.y; Bs[lk + 2][lr] = b4.z; Bs[lk + 3][lr] = b4.w;
    __syncthreads();
#pragma unroll
    for (int kk = 0; kk < BKK; ++kk) {
      float4 av = *(const float4*)&As[kk][ty * 4];
      float4 bv = *(const float4*)&Bs[kk][tx * 4];
      float aa[4] = {av.x, av.y, av.z, av.w};
      float bb[4] = {bv.x, bv.y, bv.z, bv.w};
#pragma unroll
      for (int a = 0; a < 4; ++a)
#pragma unroll
        for (int b = 0; b < 4; ++b)
          acc[a][b] = __builtin_fmaf(aa[a], bb[b], acc[a][b]);
    }
  }
  if (!transOut) {
#pragma unroll
    for (int a = 0; a < 4; ++a) {
      int i = bm + ty * 4 + a;
#pragma unroll
      for (int b = 0; b < 4; ++b) {
        int j = bn + tx * 4 + b;
        if (j < N) Cp[(size_t)i * ldC + j] = acc[a][b] + bp[j];
      }
    }
  } else {
    __syncthreads();
#pragma unroll
    for (int a = 0; a < 4; ++a)
#pragma unroll
      for (int b = 0; b < 4; ++b) {
        int jn = bn + tx * 4 + b; if (jn >= N) jn = N - 1;
        Ts[tx * 4 + b][ty * 4 + a] = acc[a][b] + bp[jn];
      }
    __syncthreads();
    const int n2 = tid >> 2, mq = (tid & 3) * 16;
    const int n = bn + n2;
    if (n < N) {
#pragma unroll
      for (int r = 0; r < 4; ++r) {
        int m0 = mq + r * 4;
        float4 v;
        v.x = Ts[n2][m0 + 0]; v.y = Ts[n2][m0 + 1];
        v.z = Ts[n2][m0 + 2]; v.w = Ts[n2][m0 + 3];
        *(float4*)(Cp + (size_t)n * ldC + bm + m0) = v;
      }
    }
  }
}

// ---------------- LSTM recurrence v3 ----------------------------------------------
// Pt: transposed pre-gates [d][500][1024], rows pre-scaled by LOG2E (2LOG2E for g).
// Whh: [d][500][125] (scaled at load). hout: [1024][256].
// 512 threads: t = 4u+sub; thread owns gate rows {g*125+u}, cols sub*32..+31.
// v_pk_fma_f32 via asm; raw lgkm-only barrier (1/step); keep-reduce butterflies.
template<bool FWD>
__device__ __forceinline__ void rec_loop(
    const float4* __restrict__ Pr, const v2f (&w)[4][16],
    float (*hb)[160], float (*hist)[128],
    float* __restrict__ hout, int d, int t, int u, int sub, bool active,
    float sA, float sB) {
  const bool b1s = (sub & 1) != 0;
  const bool b2s = (sub & 2) != 0;
  const bool wr = (sub == 0) && active;
  float cst = 0.f;
  float4 cura = Pr[FWD ? 0 : 254];
  float4 curb = Pr[FWD ? 1 : 255];
  barrier_lgkm();

  for (int cb = 0; cb < 128; ++cb) {
    int nc = (cb + 1 < 128) ? cb + 1 : cb;
    float4 nxta = Pr[FWD ? 2 * nc     : 254 - 2 * nc];
    float4 nxtb = Pr[FWD ? 2 * nc + 1 : 255 - 2 * nc];
#pragma unroll
    for (int e = 0; e < 8; ++e) {
      const int buf = e & 1;
      float pre;
      if (FWD)
        pre = (e == 0) ? cura.x : (e == 1) ? cura.y : (e == 2) ? cura.z : (e == 3) ? cura.w
            : (e == 4) ? curb.x : (e == 5) ? curb.y : (e == 6) ? curb.z : curb.w;
      else
        pre = (e == 0) ? curb.w : (e == 1) ? curb.z : (e == 2) ? curb.y : (e == 3) ? curb.x
            : (e == 4) ? cura.w : (e == 5) ? cura.z : (e == 6) ? cura.y : cura.x;
      const v4f* hp = (const v4f*)&hb[buf][36 * sub];
      v2f a0 = {0.f, 0.f}, a1 = {0.f, 0.f}, a2 = {0.f, 0.f}, a3 = {0.f, 0.f};
#pragma unroll
      for (int q = 0; q < 8; ++q) {
        v4f hv = hp[q];
        v2f ha = __builtin_shufflevector(hv, hv, 0, 1);
        v2f hc = __builtin_shufflevector(hv, hv, 2, 3);
        a0 = pkfma(w[0][2 * q], ha, a0); a0 = pkfma(w[0][2 * q + 1], hc, a0);
        a1 = pkfma(w[1][2 * q], ha, a1); a1 = pkfma(w[1][2 * q + 1], hc, a1);
        a2 = pkfma(w[2][2 * q], ha, a2); a2 = pkfma(w[2][2 * q + 1], hc, a2);
        a3 = pkfma(w[3][2 * q], ha, a3); a3 = pkfma(w[3][2 * q + 1], hc, a3);
      }
      float p0 = a0.x + a0.y, p1 = a1.x + a1.y, p2 = a2.x + a2.y, p3 = a3.x + a3.y;
      // keep-reduce over the 4 sub-chunks: lane sub ends with gate `sub`'s full dot
      float s01 = b1s ? p0 : p1, k01 = b1s ? p1 : p0;
      float r01 = k01 + dpp_xor1(s01);
      float s23 = b1s ? p2 : p3, k23 = b1s ? p3 : p2;
      float r23 = k23 + dpp_xor1(s23);
      float sv = b2s ? r01 : r23, kv = b2s ? r23 : r01;
      float x = kv + dpp_xor2(sv) + pre;        // already in exp2 domain
      float sg = frcp(1.f + fexp2(-x));
      float a = __builtin_fmaf(sA, sg, sB);     // sigmoid, or tanh for g-gate
      // gather i,f,g,o into sub0 lane
      float fg = dpp_xor1(a);
      float gg = dpp_xor2(a);
      float og = dpp_xor2(fg);
      cst = __builtin_fmaf(fg, cst, a * gg);
      float th = __builtin_fmaf(2.f, frcp(1.f + fexp2(-2.f * LOG2E * cst)), -1.f);
      float h = og * th;
      if (wr) {
        hb[buf ^ 1][u + 4 * (u >> 5)] = h;
        hist[(cb & 3) * 8 + e][u] = h;
      }
      barrier_lgkm();
    }
    if ((cb & 3) == 3) {   // flush 32 steps of h to global (stores stay in flight)
      const int S0 = (cb - 3) * 8;
#pragma unroll
      for (int k = 0; k < 8; ++k) {
        int idx = t + k * 512;
        int r = idx >> 7, u2 = idx & 127;
        if (u2 < 125) {
          int step = S0 + r;
          int time = FWD ? step : 1023 - step;
          hout[(size_t)time * 256 + d * 125 + u2] = hist[r][u2];
        }
      }
      barrier_lgkm();
    }
    cura = nxta; curb = nxtb;
  }
}

__global__ __launch_bounds__(512, 2) void k_rec(const float* __restrict__ Pt,
                                                const float* __restrict__ Whh,
                                                float* __restrict__ hout) {
  const int d = blockIdx.x;
  const int t = threadIdx.x;
  int u = t >> 2; const bool active = (u < 125); if (u > 124) u = 124;
  const int sub = t & 3;

  // weights into registers, pre-scaled into exp2 domain
  const float* Wd = Whh + (size_t)d * 500 * 125;
  v2f w[4][16];
#pragma unroll
  for (int g = 0; g < 4; ++g) {
    const float sc = (g == 2) ? 2.f * LOG2E : LOG2E;
    const float* wrp = Wd + (size_t)(g * 125 + u) * 125;
#pragma unroll
    for (int j = 0; j < 16; ++j) {
      int col = sub * 32 + 2 * j;
      v2f ww;
      ww.x = (col     < 125) ? wrp[col]     * sc : 0.f;
      ww.y = (col + 1 < 125) ? wrp[col + 1] * sc : 0.f;
      w[g][j] = ww;
    }
  }

  __shared__ __align__(16) float hb[2][160];
  __shared__ float hist[32][128];
  for (int i = t; i < 320; i += 512) ((float*)hb)[i] = 0.f;

  const int prow = sub * 125 + u;
  const float4* Pr = (const float4*)(Pt + (size_t)d * 500 * 1024 + (size_t)prow * 1024);
  const float sA = (sub == 2) ? 2.f : 1.f;
  const float sB = (sub == 2) ? -1.f : 0.f;

  if (d == 0) rec_loop<true >(Pr, w, hb, hist, hout, d, t, u, sub, active, sA, sB);
  else        rec_loop<false>(Pr, w, hb, hist, hout, d, t, u, sub, active, sA, sB);
}

// ---------------- pairwise scorer ---------------------------------------------------
__global__ __launch_bounds__(256) void k_pair(const float* __restrict__ AB,
    const float* __restrict__ fc2W, const float* __restrict__ fc2b,
    const float* __restrict__ sumw, float* __restrict__ outS,
    float* __restrict__ scoresT) {
  __shared__ float As[32][100];
  __shared__ float Bs[32][101];
  __shared__ float w2s[100];
  const int tid = threadIdx.x;
  const int i0 = blockIdx.y * 32, j0 = blockIdx.x * 32;
  for (int idx = tid; idx < 3200; idx += 256) {
    int r = idx / 100, k = idx - r * 100;
    As[r][k] = AB[(size_t)(i0 + r) * 200 + k];
    Bs[r][k] = AB[(size_t)(j0 + r) * 200 + 100 + k];
  }
  if (tid < 100) w2s[tid] = 2.f * fc2W[tid];
  __syncthreads();
  const int tx = tid & 31, ty = tid >> 5;
  float acc[4] = {0.f, 0.f, 0.f, 0.f};
#pragma unroll 4
  for (int k = 0; k < 100; ++k) {
    float b = Bs[tx][k];
    float wk2 = w2s[k];
    float bs = b * (2.f * LOG2E);
#pragma unroll
    for (int q = 0; q < 4; ++q) {
      float a = As[ty + 8 * q][k];
      float r = frcp(1.f + fexp2(__builtin_fmaf(a, 2.f * LOG2E, bs)));
      acc[q] = __builtin_fmaf(wk2, r, acc[q]);
    }
  }
  float base = sumw[0] + fc2b[0];
  const int j = j0 + tx;
#pragma unroll
  for (int q = 0; q < 4; ++q) {
    int i = i0 + ty + 8 * q;
    float val = (i != j && j != 0) ? (base - acc[q]) : 0.f;
    outS[(size_t)i * 1024 + j] = val;
    scoresT[(size_t)j * 1024 + i] = val;
  }
}

// ---------------- per-child log-softmax contribution -------------------------------
__global__ __launch_bounds__(256) void k_soft(const float* __restrict__ scoresT,
    const int* __restrict__ parents, float* __restrict__ contrib) {
  const int j = blockIdx.x, tid = threadIdx.x;
  __shared__ float red[256];
  const float* row = scoresT + (size_t)j * 1024;
  float v0 = row[tid], v1 = row[tid + 256], v2 = row[tid + 512], v3 = row[tid + 768];
  float m = fmaxf(fmaxf(v0, v1), fmaxf(v2, v3));
  red[tid] = m; __syncthreads();
  for (int off = 128; off; off >>= 1) {
    if (tid < off) red[tid] = fmaxf(red[tid], red[tid + off]);
    __syncthreads();
  }
  m = red[0]; __syncthreads();
  float s = fexp2((v0 - m) * LOG2E) + fexp2((v1 - m) * LOG2E) +
            fexp2((v2 - m) * LOG2E) + fexp2((v3 - m) * LOG2E);
  red[tid] = s; __syncthreads();
  for (int off = 128; off; off >>= 1) {
    if (tid < off) red[tid] += red[tid + off];
    __syncthreads();
  }
  if (tid == 0) {
    float S = red[0];
    int p = parents[j];
    contrib[j] = row[p] - m - flog2(S) * LN2;
  }
}

__global__ __launch_bounds__(256) void k_loss(const float* __restrict__ contrib,
                                              float* __restrict__ out) {
  __shared__ float red[256];
  int tid = threadIdx.x;
  float s = contrib[tid] + contrib[tid + 256] + contrib[tid + 512] + contrib[tid + 768];
  red[tid] = s; __syncthreads();
  for (int off = 128; off; off >>= 1) {
    if (tid < off) red[tid] += red[tid + off];
    __syncthreads();
  }
  if (tid == 0) out[0] = -red[0] * (1.f / 1024.f);
}

// ---------------- launcher ---------------------------------------------------------
extern "C" void kernel_launch(void* const* d_in, const int* in_sizes, int n_in,
                              void* d_out, int out_size, void* d_ws, size_t ws_size,
                              hipStream_t stream) {
  const float* wv   = (const float*)d_in[0];
  const int*   pidx = (const int*)d_in[1];
  const int*   par  = (const int*)d_in[2];
  const float* pemb = (const float*)d_in[3];
  const float* Wih0 = (const float*)d_in[4];
  const float* Whh0 = (const float*)d_in[5];
  const float* b0   = (const float*)d_in[6];
  const float* Wih1 = (const float*)d_in[7];
  const float* Whh1 = (const float*)d_in[8];
  const float* b1   = (const float*)d_in[9];
  const float* fc1W = (const float*)d_in[10];
  const float* fc1b = (const float*)d_in[11];
  const float* fc2W = (const float*)d_in[12];
  const float* fc2b = (const float*)d_in[13];
  float* ws = (float*)d_ws;
  // workspace layout (float offsets)
  float* X      = ws + 0;        // 1024*336
  float* Wih0p  = ws + 344064;   // 2*500*336
  float* Pt0    = ws + 680064;   // 2*500*1024
  float* h0     = ws + 1704064;  // 1024*256
  float* Wih1p  = ws + 1966208;  // 2*500*256
  float* Pt1    = ws + 2222208;  // 2*500*1024
  float* h1     = ws + 3246208;  // 1024*256
  float* Wab    = ws + 3508352;  // 200*256
  float* biasAB = ws + 3559552;  // 256
  float* AB     = ws + 3559808;  // 1024*200
  float* scT    = ws + 3764608;  // 1024*1024
  float* contrib= ws + 4813184;  // 1024
  float* sumw   = ws + 4814208;  // 1
  float* bs0    = ws + 4814212;  // 1000 (scaled biases layer 0)
  float* bs1    = ws + 4815212;  // 1000 (scaled biases layer 1)
  float* out = (float*)d_out;

  // zero padded h buffers (cols 250..255 must stay 0 for the K=256 GEMMs)
  hipMemsetAsync(h0, 0, 1024 * 256 * sizeof(float), stream);
  hipMemsetAsync(h1, 0, 1024 * 256 * sizeof(float), stream);

  k_embed <<<1024, 128, 0, stream>>>(wv, pidx, pemb, X);
  k_repack<<<1000, 128, 0, stream>>>(Wih0, Wih0p, 325, 336, 1);
  k_repack<<<1000, 128, 0, stream>>>(Wih1, Wih1p, 250, 256, 1);
  k_bscale<<<4, 256, 0, stream>>>(b0, bs0);
  k_bscale<<<4, 256, 0, stream>>>(b1, bs1);
  k_wab   <<<200, 128, 0, stream>>>(fc1W, Wab);
  k_misc  <<<1, 128, 0, stream>>>(fc1b, fc2W, biasAB, sumw);

  // layer 0 (pre-gates stored transposed: Pt[z][n][m], ldC = 1024)
  k_gemm<<<dim3(8, 16, 2), 256, 0, stream>>>(X, Wih0p, bs0, Pt0, 1024, 500, 336, 1024,
                                             500L * 336, 500L * 1024, 500L, 1);
  k_rec <<<2, 512, 0, stream>>>(Pt0, Whh0, h0);
  // layer 1
  k_gemm<<<dim3(8, 16, 2), 256, 0, stream>>>(h0, Wih1p, bs1, Pt1, 1024, 500, 256, 1024,
                                             500L * 256, 500L * 1024, 500L, 1);
  k_rec <<<2, 512, 0, stream>>>(Pt1, Whh1, h1);
  // head/child projections (fc1_b folded into head half via biasAB)
  k_gemm<<<dim3(4, 16, 1), 256, 0, stream>>>(h1, Wab, biasAB, AB, 1024, 200, 256, 200,
                                             0L, 0L, 0L, 0);
  // pairwise scores + transposed copy
  k_pair<<<dim3(32, 32), 256, 0, stream>>>(AB, fc2W, fc2b, sumw, out + 1, scT);
  // per-child log-softmax and loss
  k_soft<<<1024, 256, 0, stream>>>(scT, par, contrib);
  k_loss<<<1, 256, 0, stream>>>(contrib, out);
}